// Round 5
// baseline (256.499 us; speedup 1.0000x reference)
//
#include <hip/hip_runtime.h>
#include <stdint.h>

// VectorQuantizer: N=65536 rows, D=128, K=1024 codewords, f32.
// d_out (all f32): quantized (8388608) | indices-as-float (65536) | loss (1)
//
// score = ||c||^2 - 2 x.c via bf16-split MFMA (hi*hi + hi*lo + lo*hi).
// K-split: each block does 128 rows x 512 codewords; merge pass combines.
// Rows with top2-margin < MARGIN re-ranked exactly in f32 (batched repair).
// Loss = 1.25 * mean(||x||^2 + best_score), rowloss reduced at the end.

typedef short     bf16x8 __attribute__((ext_vector_type(8)));
typedef float     f32x4  __attribute__((ext_vector_type(4)));
typedef unsigned short u16x8 __attribute__((ext_vector_type(8)));
typedef unsigned short u16x2 __attribute__((ext_vector_type(2)));

constexpr int N_ROWS = 65536;
constexpr int K_CODES = 1024;
constexpr int D = 128;
constexpr float MARGIN = 0.03f;   // >> 30x worst-case bf16-split score error (~1e-3)

__device__ __forceinline__ unsigned short f32_to_bf16_rn(float f) {
    unsigned u = __float_as_uint(f);
    unsigned r = (u + 0x7FFFu + ((u >> 16) & 1u)) >> 16;
    return (unsigned short)r;
}
__device__ __forceinline__ float bf16_to_f32(unsigned short h) {
    return __uint_as_float(((unsigned)h) << 16);
}

__device__ __forceinline__ void gload_lds16(const void* g, void* l) {
    __builtin_amdgcn_global_load_lds(
        (const __attribute__((address_space(1))) unsigned int*)g,
        (__attribute__((address_space(3))) unsigned int*)l, 16, 0, 0);
}

// ---------------------------------------------------------------------------
// Prep: codeword norms (verified f32 math) + bf16 hi/lo planes; zero rcnt.
// Cp layout: [plane(2)][1024][128] bf16, plane stride 131072 elems (262144 B).
__global__ __launch_bounds__(64) void vq_prep_cw(const float* __restrict__ cw,
                                                 unsigned short* __restrict__ Cp,
                                                 float* __restrict__ cnorm,
                                                 int* __restrict__ rcnt) {
    const int k = blockIdx.x;
    const int lane = threadIdx.x;
    float2 v = reinterpret_cast<const float2*>(cw + (size_t)k * D)[lane];
    float s = v.x * v.x + v.y * v.y;
#pragma unroll
    for (int off = 32; off; off >>= 1) s += __shfl_down(s, off, 64);
    if (lane == 0) cnorm[k] = s;
    if (lane == 0 && k == 0) *rcnt = 0;

    unsigned short hx = f32_to_bf16_rn(v.x), hy = f32_to_bf16_rn(v.y);
    unsigned short lx = f32_to_bf16_rn(v.x - bf16_to_f32(hx));
    unsigned short ly = f32_to_bf16_rn(v.y - bf16_to_f32(hy));
    size_t off0 = (size_t)k * D + lane * 2;
    u16x2 hv; hv[0] = hx; hv[1] = hy;
    u16x2 lv; lv[0] = lx; lv[1] = ly;
    *reinterpret_cast<u16x2*>(Cp + off0) = hv;
    *reinterpret_cast<u16x2*>(Cp + 131072 + off0) = lv;
}

// ---------------------------------------------------------------------------
// Main: fused MFMA score + per-row top-2 over HALF the codebook.
// blockIdx: tile = bid>>1 (128 rows), khalf = bid&1 (512 codewords).
// 4 waves x 32 rows; chunks of 32 codewords; LDS 32KB double-buffered.
__global__ __launch_bounds__(256, 3) void vq_argmin_mfma(
    const float* __restrict__ x,
    const unsigned short* __restrict__ Cp,
    const float* __restrict__ cnorm,
    float* __restrict__ half_bv,
    float* __restrict__ half_bv2,
    int* __restrict__ half_bi,
    float* __restrict__ xnorm) {
    __shared__ unsigned char Bs[2][2][8192];  // [buf][plane][32cw * 256B swizzled]

    const int tid = threadIdx.x;
    const int wave = tid >> 6;
    const int lane = tid & 63;
    const int l15 = lane & 15;
    const int lg = lane >> 4;
    const int tile = blockIdx.x >> 1;
    const int khalf = blockIdx.x & 1;
    const int wrow = tile * 128 + wave * 32;

    // Stage chunk c (32 codewords x 2 planes = 16KB) -> 16 wave-loads, 4/wave.
    // LDS[pl][cwl][q16] = Cp[pl][khalf*512 + c*32 + cwl][q ^ ((cwl&7)<<4)]
    const char* Cpb = reinterpret_cast<const char*>(Cp);
    auto stageB = [&](int c, int b) {
#pragma unroll
        for (int u = 0; u < 4; ++u) {
            int t = wave * 4 + u;
            int pl = t >> 3;
            int cwl = (t & 7) * 4 + lg;
            int q = l15 * 16;
            const char* src = Cpb + pl * 262144 + khalf * 131072
                              + ((size_t)(c * 32 + cwl)) * 256 + (q ^ ((cwl & 7) << 4));
            void* dst = (void*)&Bs[b][pl][(t & 7) * 1024];
            gload_lds16(src, dst);
        }
    };
    stageB(0, 0);

    // A fragments: read f32 x, split to bf16 hi/lo in regs; also row sumsq.
    bf16x8 A[2][4][2];
    float xn[2] = {0.f, 0.f};
#pragma unroll
    for (int r2 = 0; r2 < 2; ++r2) {
        const float* xr0 = x + (size_t)(wrow + r2 * 16 + l15) * D;
#pragma unroll
        for (int s = 0; s < 4; ++s) {
            const float4* xf = reinterpret_cast<const float4*>(xr0 + s * 32 + lg * 8);
            float4 f0 = xf[0];
            float4 f1 = xf[1];
            float in[8] = {f0.x, f0.y, f0.z, f0.w, f1.x, f1.y, f1.z, f1.w};
            u16x8 hv, lv;
#pragma unroll
            for (int e = 0; e < 8; ++e) {
                xn[r2] += in[e] * in[e];
                unsigned short h = f32_to_bf16_rn(in[e]);
                hv[e] = h;
                lv[e] = f32_to_bf16_rn(in[e] - bf16_to_f32(h));
            }
            A[r2][s][0] = *reinterpret_cast<bf16x8*>(&hv);
            A[r2][s][1] = *reinterpret_cast<bf16x8*>(&lv);
        }
    }
    // xnorm: reduce the 4 lg-lanes holding the same row; khalf==0 writes.
#pragma unroll
    for (int r2 = 0; r2 < 2; ++r2) {
        xn[r2] += __shfl_xor(xn[r2], 16, 64);
        xn[r2] += __shfl_xor(xn[r2], 32, 64);
        if (khalf == 0 && lg == 0) xnorm[wrow + r2 * 16 + l15] = xn[r2];
    }

    float bv[2][4], bv2[2][4];
    int bi_[2][4];
#pragma unroll
    for (int r2 = 0; r2 < 2; ++r2)
#pragma unroll
        for (int i = 0; i < 4; ++i) { bv[r2][i] = 3.4e38f; bv2[r2][i] = 3.4e38f; bi_[r2][i] = 0; }

    const int cb = l15 * 256;
    const int swz = (l15 & 7) << 4;
    int kb[4];
#pragma unroll
    for (int s = 0; s < 4; ++s) kb[s] = (s * 64 + lg * 16) ^ swz;

    asm volatile("s_waitcnt vmcnt(0)" ::: "memory");
    __syncthreads();

    for (int c = 0; c < 16; ++c) {
        const int buf = c & 1;
        if (c < 15) stageB(c + 1, buf ^ 1);

        f32x4 acc[2][2];
#pragma unroll
        for (int r2 = 0; r2 < 2; ++r2)
#pragma unroll
            for (int j = 0; j < 2; ++j) acc[r2][j] = (f32x4)(0.f);

#pragma unroll
        for (int s = 0; s < 4; ++s) {
            bf16x8 bh[2], bl[2];
#pragma unroll
            for (int j = 0; j < 2; ++j) {
                int ad = j * 4096 + cb + kb[s];
                bh[j] = *reinterpret_cast<const bf16x8*>(&Bs[buf][0][ad]);
                bl[j] = *reinterpret_cast<const bf16x8*>(&Bs[buf][1][ad]);
            }
#pragma unroll
            for (int r2 = 0; r2 < 2; ++r2)
#pragma unroll
                for (int j = 0; j < 2; ++j) {
                    acc[r2][j] = __builtin_amdgcn_mfma_f32_16x16x32_bf16(
                        A[r2][s][0], bh[j], acc[r2][j], 0, 0, 0);
                    acc[r2][j] = __builtin_amdgcn_mfma_f32_16x16x32_bf16(
                        A[r2][s][0], bl[j], acc[r2][j], 0, 0, 0);
                    acc[r2][j] = __builtin_amdgcn_mfma_f32_16x16x32_bf16(
                        A[r2][s][1], bh[j], acc[r2][j], 0, 0, 0);
                }
        }

        // scores + running top-2 (cols ascend per lane -> first-min kept)
#pragma unroll
        for (int j = 0; j < 2; ++j) {
            int col = khalf * 512 + c * 32 + j * 16 + l15;
            float cn = cnorm[col];
#pragma unroll
            for (int r2 = 0; r2 < 2; ++r2)
#pragma unroll
                for (int i = 0; i < 4; ++i) {
                    float sc = cn - 2.f * acc[r2][j][i];
                    if (sc < bv[r2][i]) {
                        bv2[r2][i] = bv[r2][i];
                        bv[r2][i] = sc;
                        bi_[r2][i] = col;
                    } else if (sc < bv2[r2][i]) {
                        bv2[r2][i] = sc;
                    }
                }
        }
        asm volatile("s_waitcnt vmcnt(0)" ::: "memory");
        __syncthreads();
    }

    // Cross-lane top-2 merge over the 16 l15-lanes sharing each row.
#pragma unroll
    for (int r2 = 0; r2 < 2; ++r2)
#pragma unroll
        for (int i = 0; i < 4; ++i) {
            float v = bv[r2][i], v2 = bv2[r2][i];
            int ix = bi_[r2][i];
#pragma unroll
            for (int off = 1; off < 16; off <<= 1) {
                float ov = __shfl_xor(v, off, 64);
                float ov2 = __shfl_xor(v2, off, 64);
                int oi = __shfl_xor(ix, off, 64);
                float nv2 = fminf(fminf(v2, ov2), fmaxf(v, ov));
                if (ov < v || (ov == v && oi < ix)) { v = ov; ix = oi; }
                v2 = nv2;
            }
            if (l15 == 0) {
                int row = wrow + r2 * 16 + lg * 4 + i;
                int o = khalf * N_ROWS + row;
                half_bv[o] = v;
                half_bv2[o] = v2;
                half_bi[o] = ix;
            }
        }
}

// ---------------------------------------------------------------------------
// Merge halves: final idx, qout row (straight-through == codeword within 1ulp),
// rowloss = ||x||^2 + best_score; flag rows with margin < MARGIN for repair.
__global__ __launch_bounds__(256) void vq_merge(const float* __restrict__ cw,
                                                const float* __restrict__ half_bv,
                                                const float* __restrict__ half_bv2,
                                                const int* __restrict__ half_bi,
                                                const float* __restrict__ xnorm,
                                                float* __restrict__ out_idx_f,
                                                float* __restrict__ qout,
                                                float* __restrict__ rowloss,
                                                int* __restrict__ rcnt,
                                                int* __restrict__ rrows) {
    const int t = threadIdx.x;
    const int row = blockIdx.x * 8 + (t >> 5);
    const int d4 = t & 31;

    float v0 = half_bv[row], v0b = half_bv2[row];
    int i0 = half_bi[row];
    float v1 = half_bv[N_ROWS + row], v1b = half_bv2[N_ROWS + row];
    int i1 = half_bi[N_ROWS + row];

    bool take0 = (v0 < v1) || (v0 == v1 && i0 <= i1);
    float best = take0 ? v0 : v1;
    int bidx = take0 ? i0 : i1;
    float second = take0 ? fminf(v1, v0b) : fminf(v0, v1b);

    float4 q4 = reinterpret_cast<const float4*>(cw)[(size_t)bidx * 32 + d4];
    reinterpret_cast<float4*>(qout)[(size_t)row * 32 + d4] = q4;

    if (d4 == 0) {
        out_idx_f[row] = (float)bidx;
        rowloss[row] = xnorm[row] + best;
        if (second - best < MARGIN) {
            int p = atomicAdd(rcnt, 1);
            rrows[p] = row;
        }
    }
}

// ---------------------------------------------------------------------------
// Batched exact repair: 16 flagged rows share one codebook stream.
// thread t: row r = t&15, quarter q = t>>4 (64 codewords), k-tiled by 8 so
// each LDS x-read feeds 8 codewords. Exact f32, ascending-k first-min.
__global__ __launch_bounds__(256) void vq_repair(const float* __restrict__ x,
                                                 const float* __restrict__ cw,
                                                 const float* __restrict__ cnorm,
                                                 const float* __restrict__ xnorm,
                                                 const int* __restrict__ rcnt,
                                                 const int* __restrict__ rrows,
                                                 float* __restrict__ out_idx_f,
                                                 float* __restrict__ qout,
                                                 float* __restrict__ rowloss) {
    __shared__ float xs[16][132];
    __shared__ int rowids[16];
    __shared__ float sval[16][16];
    __shared__ int sidx[16][16];
    __shared__ int fidx[16];

    const int t = threadIdx.x;
    const int count = *rcnt;
    const float4* cw4 = reinterpret_cast<const float4*>(cw);

    for (int g = blockIdx.x; g * 16 < count; g += 256) {
        int nrows = min(16, count - g * 16);
        __syncthreads();  // protect shared reuse across iterations
        if (t < 16) rowids[t] = rrows[g * 16 + (t < nrows ? t : 0)];
        __syncthreads();
        for (int i = t; i < 512; i += 256) {
            int r = i >> 5, d4 = i & 31;
            *reinterpret_cast<float4*>(&xs[r][d4 * 4]) =
                reinterpret_cast<const float4*>(x)[(size_t)rowids[r] * 32 + d4];
        }
        __syncthreads();

        const int r = t & 15;
        const int qq = t >> 4;
        float bv = 3.4e38f;
        int bi = 0;
#pragma unroll 2
        for (int kt = 0; kt < 8; ++kt) {
            float a[8] = {0.f, 0.f, 0.f, 0.f, 0.f, 0.f, 0.f, 0.f};
            int k0 = qq * 64 + kt * 8;
            for (int d4 = 0; d4 < 32; ++d4) {
                float4 xv = *reinterpret_cast<const float4*>(&xs[r][d4 * 4]);
#pragma unroll
                for (int kk = 0; kk < 8; ++kk) {
                    float4 cv = cw4[(size_t)(k0 + kk) * 32 + d4];
                    a[kk] += xv.x * cv.x + xv.y * cv.y + xv.z * cv.z + xv.w * cv.w;
                }
            }
#pragma unroll
            for (int kk = 0; kk < 8; ++kk) {
                int k = k0 + kk;
                float sc = cnorm[k] - 2.f * a[kk];
                if (sc < bv) { bv = sc; bi = k; }
            }
        }
        sval[r][qq] = bv;
        sidx[r][qq] = bi;
        __syncthreads();
        if (t < 16) {
            float fv = sval[t][0];
            int fi = sidx[t][0];
#pragma unroll
            for (int q2 = 1; q2 < 16; ++q2) {
                float v = sval[t][q2];
                int ii = sidx[t][q2];
                if (v < fv || (v == fv && ii < fi)) { fv = v; fi = ii; }
            }
            fidx[t] = fi;
            if (t < nrows) {
                int row = rowids[t];
                out_idx_f[row] = (float)fi;
                rowloss[row] = xnorm[row] + fv;
            }
        }
        __syncthreads();
        for (int i = t; i < 512; i += 256) {
            int rr = i >> 5, d4 = i & 31;
            float4 q4 = cw4[(size_t)fidx[rr] * 32 + d4];
            reinterpret_cast<float4*>(qout)[(size_t)rowids[rr] * 32 + d4] = q4;
        }
    }
}

// ---------------------------------------------------------------------------
// Final: loss = 1.25 * sum(rowloss) / (N*D)
__global__ __launch_bounds__(1024) void vq_loss_final(const float* __restrict__ rowloss,
                                                      float* __restrict__ out_loss) {
    double s = 0.0;
    for (int i = threadIdx.x; i < N_ROWS; i += 1024) s += (double)rowloss[i];
#pragma unroll
    for (int off = 32; off; off >>= 1) s += __shfl_down(s, off, 64);
    __shared__ double wsum[16];
    if ((threadIdx.x & 63) == 0) wsum[threadIdx.x >> 6] = s;
    __syncthreads();
    if (threadIdx.x == 0) {
        double tot = 0.0;
#pragma unroll
        for (int i = 0; i < 16; ++i) tot += wsum[i];
        *out_loss = (float)(tot * (1.25 / (double)((size_t)N_ROWS * D)));
    }
}

// ---------------------------------------------------------------------------
extern "C" void kernel_launch(void* const* d_in, const int* in_sizes, int n_in,
                              void* d_out, int out_size, void* d_ws, size_t ws_size,
                              hipStream_t stream) {
    const float* x = (const float*)d_in[0];
    const float* cw = (const float*)d_in[1];

    float* qout = (float*)d_out;                                    // 8388608 f32
    float* out_idx_f = qout + (size_t)N_ROWS * D;                   // 65536 f32
    float* out_loss = out_idx_f + N_ROWS;                           // 1 f32

    // Scratch (~2.9 MB): Cp | cnorm | rcnt | rrows | half_bv | half_bv2 | half_bi | xnorm | rowloss
    char* w = (char*)d_ws;
    unsigned short* Cp = (unsigned short*)w;          w += 524288;
    float* cnorm = (float*)w;                         w += 4096;
    int* rcnt = (int*)w;                              w += 256;
    int* rrows = (int*)w;                             w += 262144;
    float* half_bv = (float*)w;                       w += 524288;
    float* half_bv2 = (float*)w;                      w += 524288;
    int* half_bi = (int*)w;                           w += 524288;
    float* xnorm = (float*)w;                         w += 262144;
    float* rowloss = (float*)w;                       w += 262144;

    vq_prep_cw<<<K_CODES, 64, 0, stream>>>(cw, Cp, cnorm, rcnt);
    vq_argmin_mfma<<<(N_ROWS / 128) * 2, 256, 0, stream>>>(
        x, Cp, cnorm, half_bv, half_bv2, half_bi, xnorm);
    vq_merge<<<N_ROWS / 8, 256, 0, stream>>>(
        cw, half_bv, half_bv2, half_bi, xnorm, out_idx_f, qout, rowloss, rcnt, rrows);
    vq_repair<<<256, 256, 0, stream>>>(
        x, cw, cnorm, xnorm, rcnt, rrows, out_idx_f, qout, rowloss);
    vq_loss_final<<<1, 1024, 0, stream>>>(rowloss, out_loss);
}

// Round 6
// 255.243 us; speedup vs baseline: 1.0049x; 1.0049x over previous
//
#include <hip/hip_runtime.h>
#include <stdint.h>

// VectorQuantizer: N=65536 rows, D=128, K=1024 codewords, f32.
// d_out (all f32): quantized (8388608) | indices-as-float (65536) | loss (1)
//
// score = ||c||^2 - 2 x.c via bf16-split MFMA (hi*hi + hi*lo + lo*hi).
// K-split: block = 128 rows x 512 codewords; merge combines halves.
// Rows with top2-margin < MARGIN re-ranked exactly in f32 (batched repair).
// Loss = 1.25 * mean(||x||^2 + best_score), accumulated via per-block atomics.

typedef short     bf16x8 __attribute__((ext_vector_type(8)));
typedef float     f32x4  __attribute__((ext_vector_type(4)));
typedef unsigned short u16x8 __attribute__((ext_vector_type(8)));
typedef unsigned short u16x2 __attribute__((ext_vector_type(2)));

constexpr int N_ROWS = 65536;
constexpr int K_CODES = 1024;
constexpr int D = 128;
// Error budget: |approx-exact| per score <= ~2e-3 (x_lo*c_lo term ~4e-4 +
// bf16-residual cross terms + f32 accum). Comparing two scores: <=4e-3.
// MARGIN 0.01 = 2.5x safety; cuts repair count ~3x vs 0.03.
constexpr float MARGIN = 0.01f;

__device__ __forceinline__ unsigned short f32_to_bf16_rn(float f) {
    unsigned u = __float_as_uint(f);
    unsigned r = (u + 0x7FFFu + ((u >> 16) & 1u)) >> 16;
    return (unsigned short)r;
}
__device__ __forceinline__ float bf16_to_f32(unsigned short h) {
    return __uint_as_float(((unsigned)h) << 16);
}

__device__ __forceinline__ void gload_lds16(const void* g, void* l) {
    __builtin_amdgcn_global_load_lds(
        (const __attribute__((address_space(1))) unsigned int*)g,
        (__attribute__((address_space(3))) unsigned int*)l, 16, 0, 0);
}

// ---------------------------------------------------------------------------
// Prep: codeword norms (verified f32 order) + bf16 hi/lo planes; zero rcnt/acc.
__global__ __launch_bounds__(64) void vq_prep_cw(const float* __restrict__ cw,
                                                 unsigned short* __restrict__ Cp,
                                                 float* __restrict__ cnorm,
                                                 int* __restrict__ rcnt,
                                                 double* __restrict__ acc) {
    const int k = blockIdx.x;
    const int lane = threadIdx.x;
    float2 v = reinterpret_cast<const float2*>(cw + (size_t)k * D)[lane];
    float s = v.x * v.x + v.y * v.y;
#pragma unroll
    for (int off = 32; off; off >>= 1) s += __shfl_down(s, off, 64);
    if (lane == 0) cnorm[k] = s;
    if (lane == 0 && k == 0) { *rcnt = 0; *acc = 0.0; }

    unsigned short hx = f32_to_bf16_rn(v.x), hy = f32_to_bf16_rn(v.y);
    unsigned short lx = f32_to_bf16_rn(v.x - bf16_to_f32(hx));
    unsigned short ly = f32_to_bf16_rn(v.y - bf16_to_f32(hy));
    size_t off0 = (size_t)k * D + lane * 2;
    u16x2 hv; hv[0] = hx; hv[1] = hy;
    u16x2 lv; lv[0] = lx; lv[1] = ly;
    *reinterpret_cast<u16x2*>(Cp + off0) = hv;
    *reinterpret_cast<u16x2*>(Cp + 131072 + off0) = lv;
}

// ---------------------------------------------------------------------------
// Main: fused MFMA score + per-row top-2 over half the codebook.
// T4 schedule: 3 LDS buffers, counted vmcnt(4) fused with raw s_barrier;
// prefetch stays in flight across barriers (never drain to 0 mid-loop).
__global__ __launch_bounds__(256, 3) void vq_argmin_mfma(
    const float* __restrict__ x,
    const unsigned short* __restrict__ Cp,
    const float* __restrict__ cnorm,
    float* __restrict__ half_bv,
    float* __restrict__ half_bv2,
    int* __restrict__ half_bi,
    float* __restrict__ xnorm) {
    __shared__ unsigned char Bs[3][2][8192];  // 48KB: [buf][plane][32cw * 256B swz]

    const int tid = threadIdx.x;
    const int wave = tid >> 6;
    const int lane = tid & 63;
    const int l15 = lane & 15;
    const int lg = lane >> 4;
    const int tile = blockIdx.x >> 1;
    const int khalf = blockIdx.x & 1;
    const int wrow = tile * 128 + wave * 32;

    // Stage chunk c (32 cw x 2 planes = 16KB): 16 loads, 4 per wave.
    const char* Cpb = reinterpret_cast<const char*>(Cp);
    auto stageB = [&](int c, int b) {
#pragma unroll
        for (int u = 0; u < 4; ++u) {
            int t = wave * 4 + u;
            int pl = t >> 3;
            int cwl = (t & 7) * 4 + lg;
            int q = l15 * 16;
            const char* src = Cpb + pl * 262144 + khalf * 131072
                              + ((size_t)(c * 32 + cwl)) * 256 + (q ^ ((cwl & 7) << 4));
            void* dst = (void*)&Bs[b][pl][(t & 7) * 1024];
            gload_lds16(src, dst);
        }
    };
    stageB(0, 0);

    // A fragments: f32 x -> bf16 hi/lo in regs; row sumsq on the side.
    bf16x8 A[2][4][2];
    float xn[2] = {0.f, 0.f};
#pragma unroll
    for (int r2 = 0; r2 < 2; ++r2) {
        const float* xr0 = x + (size_t)(wrow + r2 * 16 + l15) * D;
#pragma unroll
        for (int s = 0; s < 4; ++s) {
            const float4* xf = reinterpret_cast<const float4*>(xr0 + s * 32 + lg * 8);
            float4 f0 = xf[0];
            float4 f1 = xf[1];
            float in[8] = {f0.x, f0.y, f0.z, f0.w, f1.x, f1.y, f1.z, f1.w};
            u16x8 hv, lv;
#pragma unroll
            for (int e = 0; e < 8; ++e) {
                xn[r2] += in[e] * in[e];
                unsigned short h = f32_to_bf16_rn(in[e]);
                hv[e] = h;
                lv[e] = f32_to_bf16_rn(in[e] - bf16_to_f32(h));
            }
            A[r2][s][0] = *reinterpret_cast<bf16x8*>(&hv);
            A[r2][s][1] = *reinterpret_cast<bf16x8*>(&lv);
        }
    }
#pragma unroll
    for (int r2 = 0; r2 < 2; ++r2) {
        xn[r2] += __shfl_xor(xn[r2], 16, 64);
        xn[r2] += __shfl_xor(xn[r2], 32, 64);
        if (khalf == 0 && lg == 0) xnorm[wrow + r2 * 16 + l15] = xn[r2];
    }

    stageB(1, 1);

    float bv[2][4], bv2[2][4];
    int bi_[2][4];
#pragma unroll
    for (int r2 = 0; r2 < 2; ++r2)
#pragma unroll
        for (int i = 0; i < 4; ++i) { bv[r2][i] = 3.4e38f; bv2[r2][i] = 3.4e38f; bi_[r2][i] = 0; }

    const int cb = l15 * 256;
    const int swz = (l15 & 7) << 4;
    int kb[4];
#pragma unroll
    for (int s = 0; s < 4; ++s) kb[s] = (s * 64 + lg * 16) ^ swz;

    auto computeChunk = [&](int c, int buf) {
        f32x4 acc[2][2];
#pragma unroll
        for (int r2 = 0; r2 < 2; ++r2)
#pragma unroll
            for (int j = 0; j < 2; ++j) acc[r2][j] = (f32x4)(0.f);

        __builtin_amdgcn_s_setprio(1);
#pragma unroll
        for (int s = 0; s < 4; ++s) {
            bf16x8 bh[2], bl[2];
#pragma unroll
            for (int j = 0; j < 2; ++j) {
                int ad = j * 4096 + cb + kb[s];
                bh[j] = *reinterpret_cast<const bf16x8*>(&Bs[buf][0][ad]);
                bl[j] = *reinterpret_cast<const bf16x8*>(&Bs[buf][1][ad]);
            }
#pragma unroll
            for (int r2 = 0; r2 < 2; ++r2)
#pragma unroll
                for (int j = 0; j < 2; ++j) {
                    acc[r2][j] = __builtin_amdgcn_mfma_f32_16x16x32_bf16(
                        A[r2][s][0], bh[j], acc[r2][j], 0, 0, 0);
                    acc[r2][j] = __builtin_amdgcn_mfma_f32_16x16x32_bf16(
                        A[r2][s][0], bl[j], acc[r2][j], 0, 0, 0);
                    acc[r2][j] = __builtin_amdgcn_mfma_f32_16x16x32_bf16(
                        A[r2][s][1], bh[j], acc[r2][j], 0, 0, 0);
                }
        }
        __builtin_amdgcn_s_setprio(0);

#pragma unroll
        for (int j = 0; j < 2; ++j) {
            int col = khalf * 512 + c * 32 + j * 16 + l15;
            float cn = cnorm[col];
#pragma unroll
            for (int r2 = 0; r2 < 2; ++r2)
#pragma unroll
                for (int i = 0; i < 4; ++i) {
                    float sc = cn - 2.f * acc[r2][j][i];
                    if (sc < bv[r2][i]) {
                        bv2[r2][i] = bv[r2][i];
                        bv[r2][i] = sc;
                        bi_[r2][i] = col;
                    } else if (sc < bv2[r2][i]) {
                        bv2[r2][i] = sc;
                    }
                }
        }
    };

    // Steady state: wait own stage(c) (leave stage(c+1) in flight), barrier,
    // issue stage(c+2), compute chunk c. Write-after-read safe: stage(c+2)
    // reuses the buffer read in chunk c-1, whose ds_reads completed (consumed
    // by MFMA) before this barrier.
    int cur = 0;           // c % 3
    for (int c = 0; c < 15; ++c) {
        asm volatile("s_waitcnt vmcnt(4)\n\ts_barrier" ::: "memory");
        if (c < 14) {
            int stg = cur + 2;
            if (stg >= 3) stg -= 3;
            stageB(c + 2, stg);
        }
        computeChunk(c, cur);
        cur = (cur == 2) ? 0 : cur + 1;
    }
    asm volatile("s_waitcnt vmcnt(0)\n\ts_barrier" ::: "memory");
    computeChunk(15, cur);

    // Cross-lane top-2 merge over the 16 l15-lanes sharing each row.
#pragma unroll
    for (int r2 = 0; r2 < 2; ++r2)
#pragma unroll
        for (int i = 0; i < 4; ++i) {
            float v = bv[r2][i], v2 = bv2[r2][i];
            int ix = bi_[r2][i];
#pragma unroll
            for (int off = 1; off < 16; off <<= 1) {
                float ov = __shfl_xor(v, off, 64);
                float ov2 = __shfl_xor(v2, off, 64);
                int oi = __shfl_xor(ix, off, 64);
                float nv2 = fminf(fminf(v2, ov2), fmaxf(v, ov));
                if (ov < v || (ov == v && oi < ix)) { v = ov; ix = oi; }
                v2 = nv2;
            }
            if (l15 == 0) {
                int row = wrow + r2 * 16 + lg * 4 + i;
                int o = khalf * N_ROWS + row;
                half_bv[o] = v;
                half_bv2[o] = v2;
                half_bi[o] = ix;
            }
        }
}

// ---------------------------------------------------------------------------
// Merge halves: final idx, qout row, rowloss; flag margin < MARGIN; per-block
// loss partial -> ONE f64 atomic per block.
__global__ __launch_bounds__(256) void vq_merge(const float* __restrict__ cw,
                                                const float* __restrict__ half_bv,
                                                const float* __restrict__ half_bv2,
                                                const int* __restrict__ half_bi,
                                                const float* __restrict__ xnorm,
                                                float* __restrict__ out_idx_f,
                                                float* __restrict__ qout,
                                                float* __restrict__ rowloss,
                                                int* __restrict__ rcnt,
                                                int* __restrict__ rrows,
                                                double* __restrict__ acc) {
    const int t = threadIdx.x;
    const int d4 = t & 31;
    double lsum = 0.0;

    for (int it = 0; it < 32; ++it) {
        int row = blockIdx.x * 256 + it * 8 + (t >> 5);
        float v0 = half_bv[row], v0b = half_bv2[row];
        int i0 = half_bi[row];
        float v1 = half_bv[N_ROWS + row], v1b = half_bv2[N_ROWS + row];
        int i1 = half_bi[N_ROWS + row];

        bool take0 = (v0 < v1) || (v0 == v1 && i0 <= i1);
        float best = take0 ? v0 : v1;
        int bidx = take0 ? i0 : i1;
        float second = take0 ? fminf(v1, v0b) : fminf(v0, v1b);

        float4 q4 = reinterpret_cast<const float4*>(cw)[(size_t)bidx * 32 + d4];
        reinterpret_cast<float4*>(qout)[(size_t)row * 32 + d4] = q4;

        if (d4 == 0) {
            out_idx_f[row] = (float)bidx;
            float rl = xnorm[row] + best;
            rowloss[row] = rl;
            lsum += (double)rl;
            if (second - best < MARGIN) {
                int p = atomicAdd(rcnt, 1);
                rrows[p] = row;
            }
        }
    }
#pragma unroll
    for (int off = 32; off; off >>= 1) lsum += __shfl_down(lsum, off, 64);
    __shared__ double wsum[4];
    if ((t & 63) == 0) wsum[t >> 6] = lsum;
    __syncthreads();
    if (t == 0) atomicAdd(acc, wsum[0] + wsum[1] + wsum[2] + wsum[3]);
}

// ---------------------------------------------------------------------------
// Batched exact repair: 16 flagged rows share one codebook stream. Updates
// idx/qout/rowloss and accumulates (new-old) loss deltas, 1 atomic per block.
__global__ __launch_bounds__(256) void vq_repair(const float* __restrict__ x,
                                                 const float* __restrict__ cw,
                                                 const float* __restrict__ cnorm,
                                                 const float* __restrict__ xnorm,
                                                 const int* __restrict__ rcnt,
                                                 const int* __restrict__ rrows,
                                                 float* __restrict__ out_idx_f,
                                                 float* __restrict__ qout,
                                                 float* __restrict__ rowloss,
                                                 double* __restrict__ acc) {
    __shared__ float xs[16][132];
    __shared__ int rowids[16];
    __shared__ float sval[16][16];
    __shared__ int sidx[16][16];
    __shared__ int fidx[16];

    const int t = threadIdx.x;
    const int count = *rcnt;
    const float4* cw4 = reinterpret_cast<const float4*>(cw);
    double dsum = 0.0;

    for (int g = blockIdx.x; g * 16 < count; g += 512) {
        int nrows = min(16, count - g * 16);
        __syncthreads();
        if (t < 16) rowids[t] = rrows[g * 16 + (t < nrows ? t : 0)];
        __syncthreads();
        for (int i = t; i < 512; i += 256) {
            int r = i >> 5, d4 = i & 31;
            *reinterpret_cast<float4*>(&xs[r][d4 * 4]) =
                reinterpret_cast<const float4*>(x)[(size_t)rowids[r] * 32 + d4];
        }
        __syncthreads();

        const int r = t & 15;
        const int qq = t >> 4;
        float bv = 3.4e38f;
        int bi = 0;
#pragma unroll 2
        for (int kt = 0; kt < 8; ++kt) {
            float a[8] = {0.f, 0.f, 0.f, 0.f, 0.f, 0.f, 0.f, 0.f};
            int k0 = qq * 64 + kt * 8;
            for (int d4 = 0; d4 < 32; ++d4) {
                float4 xv = *reinterpret_cast<const float4*>(&xs[r][d4 * 4]);
#pragma unroll
                for (int kk = 0; kk < 8; ++kk) {
                    float4 cv = cw4[(size_t)(k0 + kk) * 32 + d4];
                    a[kk] += xv.x * cv.x + xv.y * cv.y + xv.z * cv.z + xv.w * cv.w;
                }
            }
#pragma unroll
            for (int kk = 0; kk < 8; ++kk) {
                int k = k0 + kk;
                float sc = cnorm[k] - 2.f * a[kk];
                if (sc < bv) { bv = sc; bi = k; }
            }
        }
        sval[r][qq] = bv;
        sidx[r][qq] = bi;
        __syncthreads();
        if (t < 16) {
            float fv = sval[t][0];
            int fi = sidx[t][0];
#pragma unroll
            for (int q2 = 1; q2 < 16; ++q2) {
                float v = sval[t][q2];
                int ii = sidx[t][q2];
                if (v < fv || (v == fv && ii < fi)) { fv = v; fi = ii; }
            }
            fidx[t] = fi;
            if (t < nrows) {
                int row = rowids[t];
                out_idx_f[row] = (float)fi;
                float nrl = xnorm[row] + fv;
                float orl = rowloss[row];
                rowloss[row] = nrl;
                dsum += (double)nrl - (double)orl;
            }
        }
        __syncthreads();
        for (int i = t; i < 512; i += 256) {
            int rr = i >> 5, d4 = i & 31;
            float4 q4 = cw4[(size_t)fidx[rr] * 32 + d4];
            reinterpret_cast<float4*>(qout)[(size_t)rowids[rr] * 32 + d4] = q4;
        }
    }
#pragma unroll
    for (int off = 32; off; off >>= 1) dsum += __shfl_down(dsum, off, 64);
    __shared__ double wsum[4];
    if ((t & 63) == 0) wsum[t >> 6] = dsum;
    __syncthreads();
    if (t == 0) {
        double b = wsum[0] + wsum[1] + wsum[2] + wsum[3];
        if (b != 0.0) atomicAdd(acc, b);
    }
}

// ---------------------------------------------------------------------------
__global__ void vq_loss_final(const double* __restrict__ acc,
                              float* __restrict__ out_loss) {
    *out_loss = (float)(*acc * (1.25 / (double)((size_t)N_ROWS * D)));
}

// ---------------------------------------------------------------------------
extern "C" void kernel_launch(void* const* d_in, const int* in_sizes, int n_in,
                              void* d_out, int out_size, void* d_ws, size_t ws_size,
                              hipStream_t stream) {
    const float* x = (const float*)d_in[0];
    const float* cw = (const float*)d_in[1];

    float* qout = (float*)d_out;                                    // 8388608 f32
    float* out_idx_f = qout + (size_t)N_ROWS * D;                   // 65536 f32
    float* out_loss = out_idx_f + N_ROWS;                           // 1 f32

    char* w = (char*)d_ws;
    unsigned short* Cp = (unsigned short*)w;          w += 524288;
    float* cnorm = (float*)w;                         w += 4096;
    int* rcnt = (int*)w;                              w += 16;
    double* acc = (double*)w;                         w += 240;
    int* rrows = (int*)w;                             w += 262144;
    float* half_bv = (float*)w;                       w += 524288;
    float* half_bv2 = (float*)w;                      w += 524288;
    int* half_bi = (int*)w;                           w += 524288;
    float* xnorm = (float*)w;                         w += 262144;
    float* rowloss = (float*)w;                       w += 262144;

    vq_prep_cw<<<K_CODES, 64, 0, stream>>>(cw, Cp, cnorm, rcnt, acc);
    vq_argmin_mfma<<<(N_ROWS / 128) * 2, 256, 0, stream>>>(
        x, Cp, cnorm, half_bv, half_bv2, half_bi, xnorm);
    vq_merge<<<N_ROWS / 256, 256, 0, stream>>>(
        cw, half_bv, half_bv2, half_bi, xnorm, out_idx_f, qout, rowloss, rcnt, rrows, acc);
    vq_repair<<<512, 256, 0, stream>>>(
        x, cw, cnorm, xnorm, rcnt, rrows, out_idx_f, qout, rowloss, acc);
    vq_loss_final<<<1, 1, 0, stream>>>(acc, out_loss);
}

// Round 7
// 225.698 us; speedup vs baseline: 1.1365x; 1.1309x over previous
//
#include <hip/hip_runtime.h>
#include <stdint.h>

// VectorQuantizer: N=65536 rows, D=128, K=1024 codewords, f32.
// d_out (all f32): quantized (8388608) | indices-as-float (65536) | loss (1)
//
// score = ||c||^2 - 2 x.c via bf16-split MFMA (hi*hi + hi*lo + lo*hi), fused
// per-row top-2 + full epilogue (idx, qout gather, rowloss, loss atomic,
// repair flags) in ONE kernel. Rows with top2-margin < MARGIN re-ranked
// exactly in f32 by batched repair. loss = 1.25*mean(||x||^2 + best_score).

typedef short     bf16x8 __attribute__((ext_vector_type(8)));
typedef float     f32x4  __attribute__((ext_vector_type(4)));
typedef unsigned short u16x8 __attribute__((ext_vector_type(8)));
typedef unsigned short u16x2 __attribute__((ext_vector_type(2)));

constexpr int N_ROWS = 65536;
constexpr int K_CODES = 1024;
constexpr int D = 128;
// Worst-case bf16-split score error ~4e-3 (all-same-sign residuals); typical
// ~1e-4. MARGIN 0.01 validated in R5/R6 (absmax = loss-rounding only).
constexpr float MARGIN = 0.01f;

__device__ __forceinline__ unsigned short f32_to_bf16_rn(float f) {
    unsigned u = __float_as_uint(f);
    unsigned r = (u + 0x7FFFu + ((u >> 16) & 1u)) >> 16;
    return (unsigned short)r;
}
__device__ __forceinline__ float bf16_to_f32(unsigned short h) {
    return __uint_as_float(((unsigned)h) << 16);
}

__device__ __forceinline__ void gload_lds16(const void* g, void* l) {
    __builtin_amdgcn_global_load_lds(
        (const __attribute__((address_space(1))) unsigned int*)g,
        (__attribute__((address_space(3))) unsigned int*)l, 16, 0, 0);
}

// ---------------------------------------------------------------------------
// Prep: codeword norms + bf16 hi/lo planes; zero rcnt/acc.
__global__ __launch_bounds__(64) void vq_prep_cw(const float* __restrict__ cw,
                                                 unsigned short* __restrict__ Cp,
                                                 float* __restrict__ cnorm,
                                                 int* __restrict__ rcnt,
                                                 double* __restrict__ acc) {
    const int k = blockIdx.x;
    const int lane = threadIdx.x;
    float2 v = reinterpret_cast<const float2*>(cw + (size_t)k * D)[lane];
    float s = v.x * v.x + v.y * v.y;
#pragma unroll
    for (int off = 32; off; off >>= 1) s += __shfl_down(s, off, 64);
    if (lane == 0) cnorm[k] = s;
    if (lane == 0 && k == 0) { *rcnt = 0; *acc = 0.0; }

    unsigned short hx = f32_to_bf16_rn(v.x), hy = f32_to_bf16_rn(v.y);
    unsigned short lx = f32_to_bf16_rn(v.x - bf16_to_f32(hx));
    unsigned short ly = f32_to_bf16_rn(v.y - bf16_to_f32(hy));
    size_t off0 = (size_t)k * D + lane * 2;
    u16x2 hv; hv[0] = hx; hv[1] = hy;
    u16x2 lv; lv[0] = lx; lv[1] = ly;
    *reinterpret_cast<u16x2*>(Cp + off0) = hv;
    *reinterpret_cast<u16x2*>(Cp + 131072 + off0) = lv;
}

// ---------------------------------------------------------------------------
// Fused argmin + epilogue. 512 blocks x 256 thr (4 waves x 32 rows), full K.
// R4-proven core: chunk=64 cw, 2-buffer LDS (64KB), drain+sync per chunk.
__global__ __launch_bounds__(256, 2) void vq_argmin_fused(
    const float* __restrict__ x,
    const unsigned short* __restrict__ Cp,
    const float* __restrict__ cnorm,
    const float* __restrict__ cw,
    float* __restrict__ out_idx_f,
    float* __restrict__ qout,
    float* __restrict__ rowloss,
    float* __restrict__ xnorm,
    int* __restrict__ rcnt,
    int* __restrict__ rrows,
    double* __restrict__ acc) {
    __shared__ unsigned char Bs[2][2][16384];  // [buf][plane][64cw * 256B swz]
    __shared__ int idx_s[128];
    __shared__ float xs_n[128];
    __shared__ double wsum[4];

    const int tid = threadIdx.x;
    const int wave = tid >> 6;
    const int lane = tid & 63;
    const int l15 = lane & 15;
    const int lg = lane >> 4;
    const int base = blockIdx.x * 128;
    const int wrow = base + wave * 32;

    // Stage chunk c (64 cw x 2 planes = 32KB): 32 loads, 8 per wave.
    const char* Cpb = reinterpret_cast<const char*>(Cp);
    auto stageB = [&](int c, int b) {
#pragma unroll
        for (int u = 0; u < 8; ++u) {
            int t = wave * 8 + u;
            int pl = t >> 4;
            int cwl = (t & 15) * 4 + lg;
            int q = l15 * 16;
            const char* src = Cpb + pl * 262144 + ((size_t)(c * 64 + cwl)) * 256
                              + (q ^ ((cwl & 7) << 4));
            void* dst = (void*)&Bs[b][pl][(t & 15) * 1024];
            gload_lds16(src, dst);
        }
    };
    stageB(0, 0);

    // A fragments: f32 x -> bf16 hi/lo in regs; row sumsq alongside.
    bf16x8 A[2][4][2];
    float xn[2] = {0.f, 0.f};
#pragma unroll
    for (int r2 = 0; r2 < 2; ++r2) {
        const float* xr0 = x + (size_t)(wrow + r2 * 16 + l15) * D;
#pragma unroll
        for (int s = 0; s < 4; ++s) {
            const float4* xf = reinterpret_cast<const float4*>(xr0 + s * 32 + lg * 8);
            float4 f0 = xf[0];
            float4 f1 = xf[1];
            float in[8] = {f0.x, f0.y, f0.z, f0.w, f1.x, f1.y, f1.z, f1.w};
            u16x8 hv, lv;
#pragma unroll
            for (int e = 0; e < 8; ++e) {
                xn[r2] += in[e] * in[e];
                unsigned short h = f32_to_bf16_rn(in[e]);
                hv[e] = h;
                lv[e] = f32_to_bf16_rn(in[e] - bf16_to_f32(h));
            }
            A[r2][s][0] = *reinterpret_cast<bf16x8*>(&hv);
            A[r2][s][1] = *reinterpret_cast<bf16x8*>(&lv);
        }
    }
    // Reduce xn across the 4 lg-lanes holding the same row; stash LDS + global.
#pragma unroll
    for (int r2 = 0; r2 < 2; ++r2) {
        xn[r2] += __shfl_xor(xn[r2], 16, 64);
        xn[r2] += __shfl_xor(xn[r2], 32, 64);
        if (lg == 0) {
            xs_n[wave * 32 + r2 * 16 + l15] = xn[r2];
            xnorm[wrow + r2 * 16 + l15] = xn[r2];
        }
    }

    float bv[2][4], bv2[2][4];
    int bi_[2][4];
#pragma unroll
    for (int r2 = 0; r2 < 2; ++r2)
#pragma unroll
        for (int i = 0; i < 4; ++i) { bv[r2][i] = 3.4e38f; bv2[r2][i] = 3.4e38f; bi_[r2][i] = 0; }

    const int cb = l15 * 256;
    const int swz = (l15 & 7) << 4;
    int kb[4];
#pragma unroll
    for (int s = 0; s < 4; ++s) kb[s] = (s * 64 + lg * 16) ^ swz;

    asm volatile("s_waitcnt vmcnt(0)" ::: "memory");
    __syncthreads();

    for (int c = 0; c < 16; ++c) {
        const int buf = c & 1;
        if (c < 15) stageB(c + 1, buf ^ 1);

        f32x4 accf[2][4];
#pragma unroll
        for (int r2 = 0; r2 < 2; ++r2)
#pragma unroll
            for (int j = 0; j < 4; ++j) accf[r2][j] = (f32x4)(0.f);

#pragma unroll
        for (int s = 0; s < 4; ++s) {
            bf16x8 bh[4], bl[4];
#pragma unroll
            for (int j = 0; j < 4; ++j) {
                int ad = j * 4096 + cb + kb[s];
                bh[j] = *reinterpret_cast<const bf16x8*>(&Bs[buf][0][ad]);
                bl[j] = *reinterpret_cast<const bf16x8*>(&Bs[buf][1][ad]);
            }
#pragma unroll
            for (int r2 = 0; r2 < 2; ++r2)
#pragma unroll
                for (int j = 0; j < 4; ++j) {
                    accf[r2][j] = __builtin_amdgcn_mfma_f32_16x16x32_bf16(
                        A[r2][s][0], bh[j], accf[r2][j], 0, 0, 0);
                    accf[r2][j] = __builtin_amdgcn_mfma_f32_16x16x32_bf16(
                        A[r2][s][0], bl[j], accf[r2][j], 0, 0, 0);
                    accf[r2][j] = __builtin_amdgcn_mfma_f32_16x16x32_bf16(
                        A[r2][s][1], bh[j], accf[r2][j], 0, 0, 0);
                }
        }

        // scores + running top-2 (cols ascend per lane -> first-min kept)
#pragma unroll
        for (int j = 0; j < 4; ++j) {
            int col = c * 64 + j * 16 + l15;
            float cn = cnorm[col];
#pragma unroll
            for (int r2 = 0; r2 < 2; ++r2)
#pragma unroll
                for (int i = 0; i < 4; ++i) {
                    float sc = cn - 2.f * accf[r2][j][i];
                    if (sc < bv[r2][i]) {
                        bv2[r2][i] = bv[r2][i];
                        bv[r2][i] = sc;
                        bi_[r2][i] = col;
                    } else if (sc < bv2[r2][i]) {
                        bv2[r2][i] = sc;
                    }
                }
        }
        asm volatile("s_waitcnt vmcnt(0)" ::: "memory");
        __syncthreads();
    }

    // Cross-lane top-2 merge; epilogue bookkeeping.
    double lsum = 0.0;
#pragma unroll
    for (int r2 = 0; r2 < 2; ++r2)
#pragma unroll
        for (int i = 0; i < 4; ++i) {
            float v = bv[r2][i], v2 = bv2[r2][i];
            int ix = bi_[r2][i];
#pragma unroll
            for (int off = 1; off < 16; off <<= 1) {
                float ov = __shfl_xor(v, off, 64);
                float ov2 = __shfl_xor(v2, off, 64);
                int oi = __shfl_xor(ix, off, 64);
                float nv2 = fminf(fminf(v2, ov2), fmaxf(v, ov));
                if (ov < v || (ov == v && oi < ix)) { v = ov; ix = oi; }
                v2 = nv2;
            }
            if (l15 == 0) {
                int rl_loc = wave * 32 + r2 * 16 + lg * 4 + i;
                int row = base + rl_loc;
                out_idx_f[row] = (float)ix;
                idx_s[rl_loc] = ix;
                float rl = xs_n[rl_loc] + v;
                rowloss[row] = rl;
                lsum += (double)rl;
                if (v2 - v < MARGIN) {
                    int p = atomicAdd(rcnt, 1);
                    rrows[p] = row;
                }
            }
        }

    // Block loss partial -> one f64 atomic.
#pragma unroll
    for (int off = 32; off; off >>= 1) lsum += __shfl_down(lsum, off, 64);
    if (lane == 0) wsum[wave] = lsum;
    __syncthreads();
    if (tid == 0) atomicAdd(acc, wsum[0] + wsum[1] + wsum[2] + wsum[3]);

    // qout gather-write: 128 rows x 512B, coalesced; codebook is L2-hot.
    const float4* cw4 = reinterpret_cast<const float4*>(cw);
    float4* q4 = reinterpret_cast<float4*>(qout);
#pragma unroll
    for (int it = 0; it < 16; ++it) {
        int i = it * 256 + tid;
        int r = i >> 5, d4 = i & 31;
        q4[(size_t)(base + r) * 32 + d4] = cw4[(size_t)idx_s[r] * 32 + d4];
    }
}

// ---------------------------------------------------------------------------
// Batched exact repair: 16 flagged rows share one codebook stream. Updates
// idx/qout/rowloss; accumulates (new-old) loss deltas, 1 atomic per block.
__global__ __launch_bounds__(256) void vq_repair(const float* __restrict__ x,
                                                 const float* __restrict__ cw,
                                                 const float* __restrict__ cnorm,
                                                 const float* __restrict__ xnorm,
                                                 const int* __restrict__ rcnt,
                                                 const int* __restrict__ rrows,
                                                 float* __restrict__ out_idx_f,
                                                 float* __restrict__ qout,
                                                 float* __restrict__ rowloss,
                                                 double* __restrict__ acc) {
    __shared__ float xs[16][132];
    __shared__ int rowids[16];
    __shared__ float sval[16][16];
    __shared__ int sidx[16][16];
    __shared__ int fidx[16];

    const int t = threadIdx.x;
    const int count = *rcnt;
    const float4* cw4 = reinterpret_cast<const float4*>(cw);
    double dsum = 0.0;

    for (int g = blockIdx.x; g * 16 < count; g += 512) {
        int nrows = min(16, count - g * 16);
        __syncthreads();
        if (t < 16) rowids[t] = rrows[g * 16 + (t < nrows ? t : 0)];
        __syncthreads();
        for (int i = t; i < 512; i += 256) {
            int r = i >> 5, d4 = i & 31;
            *reinterpret_cast<float4*>(&xs[r][d4 * 4]) =
                reinterpret_cast<const float4*>(x)[(size_t)rowids[r] * 32 + d4];
        }
        __syncthreads();

        const int r = t & 15;
        const int qq = t >> 4;
        float bv = 3.4e38f;
        int bi = 0;
#pragma unroll 2
        for (int kt = 0; kt < 8; ++kt) {
            float a[8] = {0.f, 0.f, 0.f, 0.f, 0.f, 0.f, 0.f, 0.f};
            int k0 = qq * 64 + kt * 8;
            for (int d4 = 0; d4 < 32; ++d4) {
                float4 xv = *reinterpret_cast<const float4*>(&xs[r][d4 * 4]);
#pragma unroll
                for (int kk = 0; kk < 8; ++kk) {
                    float4 cv = cw4[(size_t)(k0 + kk) * 32 + d4];
                    a[kk] += xv.x * cv.x + xv.y * cv.y + xv.z * cv.z + xv.w * cv.w;
                }
            }
#pragma unroll
            for (int kk = 0; kk < 8; ++kk) {
                int k = k0 + kk;
                float sc = cnorm[k] - 2.f * a[kk];
                if (sc < bv) { bv = sc; bi = k; }
            }
        }
        sval[r][qq] = bv;
        sidx[r][qq] = bi;
        __syncthreads();
        if (t < 16) {
            float fv = sval[t][0];
            int fi = sidx[t][0];
#pragma unroll
            for (int q2 = 1; q2 < 16; ++q2) {
                float v = sval[t][q2];
                int ii = sidx[t][q2];
                if (v < fv || (v == fv && ii < fi)) { fv = v; fi = ii; }
            }
            fidx[t] = fi;
            if (t < nrows) {
                int row = rowids[t];
                out_idx_f[row] = (float)fi;
                float nrl = xnorm[row] + fv;
                float orl = rowloss[row];
                rowloss[row] = nrl;
                dsum += (double)nrl - (double)orl;
            }
        }
        __syncthreads();
        for (int i = t; i < 512; i += 256) {
            int rr = i >> 5, d4 = i & 31;
            float4 q4 = cw4[(size_t)fidx[rr] * 32 + d4];
            reinterpret_cast<float4*>(qout)[(size_t)rowids[rr] * 32 + d4] = q4;
        }
    }
#pragma unroll
    for (int off = 32; off; off >>= 1) dsum += __shfl_down(dsum, off, 64);
    __shared__ double wsum[4];
    if ((t & 63) == 0) wsum[t >> 6] = dsum;
    __syncthreads();
    if (t == 0) {
        double b = wsum[0] + wsum[1] + wsum[2] + wsum[3];
        if (b != 0.0) atomicAdd(acc, b);
    }
}

// ---------------------------------------------------------------------------
__global__ void vq_loss_final(const double* __restrict__ acc,
                              float* __restrict__ out_loss) {
    *out_loss = (float)(*acc * (1.25 / (double)((size_t)N_ROWS * D)));
}

// ---------------------------------------------------------------------------
extern "C" void kernel_launch(void* const* d_in, const int* in_sizes, int n_in,
                              void* d_out, int out_size, void* d_ws, size_t ws_size,
                              hipStream_t stream) {
    const float* x = (const float*)d_in[0];
    const float* cw = (const float*)d_in[1];

    float* qout = (float*)d_out;                                    // 8388608 f32
    float* out_idx_f = qout + (size_t)N_ROWS * D;                   // 65536 f32
    float* out_loss = out_idx_f + N_ROWS;                           // 1 f32

    char* w = (char*)d_ws;
    unsigned short* Cp = (unsigned short*)w;          w += 524288;
    float* cnorm = (float*)w;                         w += 4096;
    int* rcnt = (int*)w;                              w += 16;
    double* acc = (double*)w;                         w += 240;
    int* rrows = (int*)w;                             w += 262144;
    float* xnorm = (float*)w;                         w += 262144;
    float* rowloss = (float*)w;                       w += 262144;

    vq_prep_cw<<<K_CODES, 64, 0, stream>>>(cw, Cp, cnorm, rcnt, acc);
    vq_argmin_fused<<<N_ROWS / 128, 256, 0, stream>>>(
        x, Cp, cnorm, cw, out_idx_f, qout, rowloss, xnorm, rcnt, rrows, acc);
    vq_repair<<<512, 256, 0, stream>>>(
        x, cw, cnorm, xnorm, rcnt, rrows, out_idx_f, qout, rowloss, acc);
    vq_loss_final<<<1, 1, 0, stream>>>(acc, out_loss);
}